// Round 1
// 675.947 us; speedup vs baseline: 1.0342x; 1.0342x over previous
//
#include <hip/hip_runtime.h>

#define DD 300
#define KP 320                      // padded K (10 chunks of 32)
#define NT 19                       // n-tiles of 16 (covers 304)
#define NCH 10                      // k-chunks
#define PLANE_SH 9728               // shorts per W plane-chunk: 304 rows x 32 k
#define WB_SH (2 * PLANE_SH)        // one staging buffer (hi+lo) = 19456 shorts
#define SROW_ST 312                 // shorts per s-row: 16B-aligned, 2-way-bank stride
#define SPLANE_SH (64 * SROW_ST)    // 19968 shorts per s plane (64 rows)

typedef __attribute__((ext_vector_type(8))) short short8;
typedef __attribute__((ext_vector_type(4))) float f32x4;

__device__ __forceinline__ unsigned short bf16_rne(float x) {
    union { float f; unsigned u; } v; v.f = x;
    v.u += 0x7FFF + ((v.u >> 16) & 1);
    return (unsigned short)(v.u >> 16);
}
__device__ __forceinline__ float bf16_to_f32(unsigned short h) {
    union { unsigned u; float f; } v; v.u = (unsigned)h << 16;
    return v.f;
}

// split Wl (n,k == B-frag layout) into padded bf16 hi/lo planes [KP][KP]
__global__ void split_w(const float* __restrict__ Wl, short* __restrict__ Whi, short* __restrict__ Wlo) {
    int idx = blockIdx.x * 256 + threadIdx.x;
    if (idx >= KP * KP) return;
    int n = idx / KP, k = idx % KP;
    float v = (n < DD && k < DD) ? Wl[n * DD + k] : 0.f;
    unsigned short hi = bf16_rne(v);
    Whi[idx] = (short)hi;
    Wlo[idx] = (short)bf16_rne(v - bf16_to_f32(hi));
}

// Fused sub-tree kernel: 4 levels per block (128 -> 64 -> 32 -> 16 rows).
// Inter-level activations live in LDS as bf16 hi/lo PAIRSUM planes (identical
// values the old kernel fed to MFMA, so numerics are unchanged). W chunk is
// double-buffered -> one barrier per K-chunk. Level projection reduced via the
// proven wbuf-scratch + reducer-thread pattern. MODE 0 additionally fuses the
// level-0 projection into the level-1 gather (in-register partials + shfl_xor).
template<int MODE>   // 0: gather-pair entry (embedding+ids) + level-0 proj; 1: direct-row entry
__global__ __launch_bounds__(256, 1) void tree_fused(
    const float* __restrict__ src, const int* __restrict__ ids,
    const short* __restrict__ Whi, const short* __restrict__ Wlo,
    const float* __restrict__ bl, const float* __restrict__ Wp,
    const float* __restrict__ bp, float* __restrict__ out,
    float* __restrict__ sdst, int l_entry)
{
    __shared__ __align__(16) short wbuf[2 * WB_SH];       // 77824 B: double-buffered W chunk (+pj scratch)
    __shared__ __align__(16) short sbuf[2 * SPLANE_SH];   // 79872 B: hi plane | lo plane of pairsums
    const int tid = threadIdx.x;
    const int wid = tid >> 6, lane = tid & 63;
    const int r = lane & 15, q = lane >> 4;
    const int blk = blockIdx.x;

    // zero the k-pad cols [304,312) of both s planes (read by chunk 9, q==2)
    for (int i = tid; i < 64 * 8 * 2; i += 256) {
        int pl = i >> 9, j = i & 511;
        sbuf[pl * SPLANE_SH + (j >> 3) * SROW_ST + 304 + (j & 7)] = 0;
    }

    auto stage = [&](int c, int bsel) {
        short* wb = &wbuf[bsel * WB_SH];
        for (int t2 = wid; t2 < 2 * NT; t2 += 4) {
            int pl = t2 >= NT ? 1 : 0;
            int ss = t2 - pl * NT;
            const short* gpl = pl ? Wlo : Whi;
            short8 v = *(const short8*)(gpl + (long)(ss * 16 + (lane >> 2)) * KP + c * 32 + (lane & 3) * 8);
            *(short8*)&wb[pl * PLANE_SH + ss * 512 + lane * 8] = v;
        }
    };

    float pr[4][3] = {};            // MODE0: level-0 projection partials (4 leaves/lane)
    f32x4 acc0[NT], acc1[NT];

    #pragma unroll 1
    for (int s = 0; s < 4; ++s) {
        const int n_l = 128 >> s;                  // rows at this level (always multiple of 16)
        const bool actA = (wid * 32) < n_l;
        const bool actB = (wid * 32 + 16) < n_l;   // actB implies actA
        const int rowA = wid * 32 + r;

        #pragma unroll
        for (int t = 0; t < NT; ++t)
            #pragma unroll
            for (int i = 0; i < 4; ++i) { acc0[t][i] = 0.f; acc1[t][i] = 0.f; }

        __syncthreads();                           // wbuf free (reducers done), sbuf writes visible
        stage(0, 0);

        if (s == 0) {
            // ---- entry level: x from global (gathered pairs or direct rows)
            const float *p0, *p1, *p2, *p3;
            {
                long mA = (long)blk * 128 + rowA, mB = mA + 16;
                if (MODE == 0) {
                    p0 = src + (long)ids[2 * mA] * DD;
                    p1 = src + (long)ids[2 * mA + 1] * DD;
                    p2 = src + (long)ids[2 * mB] * DD;
                    p3 = src + (long)ids[2 * mB + 1] * DD;
                } else {
                    p0 = src + mA * DD; p1 = p0;
                    p2 = src + mB * DD; p3 = p2;
                }
            }
            f32x4 xc[8], xn[8];
            auto loadx = [&](int c, f32x4* x) {
                int kk = c * 32 + q * 8;
                if (MODE == 0) {
                    if (kk + 8 <= DD) {
                        x[0] = *(const f32x4*)(p0 + kk); x[1] = *(const f32x4*)(p0 + kk + 4);
                        x[2] = *(const f32x4*)(p1 + kk); x[3] = *(const f32x4*)(p1 + kk + 4);
                        x[4] = *(const f32x4*)(p2 + kk); x[5] = *(const f32x4*)(p2 + kk + 4);
                        x[6] = *(const f32x4*)(p3 + kk); x[7] = *(const f32x4*)(p3 + kk + 4);
                    } else {
                        const float* ps[4] = {p0, p1, p2, p3};
                        #pragma unroll
                        for (int j = 0; j < 4; ++j)
                            #pragma unroll
                            for (int i = 0; i < 8; ++i) {
                                int kg = kk + i;
                                x[j * 2 + (i >> 2)][i & 3] = (kg < DD) ? ps[j][kg] : 0.f;
                            }
                    }
                } else {
                    if (kk + 8 <= DD) {
                        x[0] = *(const f32x4*)(p0 + kk); x[1] = *(const f32x4*)(p0 + kk + 4);
                        x[2] = *(const f32x4*)(p2 + kk); x[3] = *(const f32x4*)(p2 + kk + 4);
                    } else {
                        #pragma unroll
                        for (int i = 0; i < 8; ++i) {
                            int kg = kk + i;
                            x[(i >> 2)][i & 3]     = (kg < DD) ? p0[kg] : 0.f;
                            x[2 + (i >> 2)][i & 3] = (kg < DD) ? p2[kg] : 0.f;
                        }
                    }
                }
            };
            const int NX = (MODE == 0) ? 8 : 4;
            loadx(0, xc);
            #pragma unroll 1
            for (int c = 0; c < NCH; ++c) {
                __syncthreads();                               // buf[c&1] staged & visible
                if (c + 1 < NCH) { stage(c + 1, (c + 1) & 1); loadx(c + 1, xn); }
                f32x4 sA0, sA1, sB0, sB1;
                if (MODE == 0) { sA0 = xc[0] + xc[2]; sA1 = xc[1] + xc[3]; sB0 = xc[4] + xc[6]; sB1 = xc[5] + xc[7]; }
                else           { sA0 = xc[0]; sA1 = xc[1]; sB0 = xc[2]; sB1 = xc[3]; }
                short8 xhi, xlo, yhi, ylo;
                #pragma unroll
                for (int i = 0; i < 4; ++i) {
                    unsigned short h; float v;
                    v = sA0[i]; h = bf16_rne(v); xhi[i]     = (short)h; xlo[i]     = (short)bf16_rne(v - bf16_to_f32(h));
                    v = sA1[i]; h = bf16_rne(v); xhi[4 + i] = (short)h; xlo[4 + i] = (short)bf16_rne(v - bf16_to_f32(h));
                    v = sB0[i]; h = bf16_rne(v); yhi[i]     = (short)h; ylo[i]     = (short)bf16_rne(v - bf16_to_f32(h));
                    v = sB1[i]; h = bf16_rne(v); yhi[4 + i] = (short)h; ylo[4 + i] = (short)bf16_rne(v - bf16_to_f32(h));
                }
                if (MODE == 0) {
                    // fused level-0 projection partials off the in-register gather
                    int kk = c * 32 + q * 8;
                    #pragma unroll
                    for (int i = 0; i < 8; ++i) {
                        int kg = kk + i;
                        float w0 = (kg < DD) ? Wp[kg] : 0.f;
                        float w1 = (kg < DD) ? Wp[DD + kg] : 0.f;
                        float w2 = (kg < DD) ? Wp[2 * DD + kg] : 0.f;
                        #pragma unroll
                        for (int j = 0; j < 4; ++j) {
                            float xv = xc[j * 2 + (i >> 2)][i & 3];
                            pr[j][0] += xv * w0; pr[j][1] += xv * w1; pr[j][2] += xv * w2;
                        }
                    }
                }
                const short* bhp = &wbuf[(c & 1) * WB_SH + r * 32 + q * 8];
                const short* bop = bhp + PLANE_SH;
                #pragma unroll
                for (int t = 0; t < NT; ++t) {
                    short8 bh = *(const short8*)(bhp + t * 512);
                    short8 bo = *(const short8*)(bop + t * 512);
                    acc0[t] = __builtin_amdgcn_mfma_f32_16x16x32_bf16(xhi, bh, acc0[t], 0, 0, 0);
                    acc1[t] = __builtin_amdgcn_mfma_f32_16x16x32_bf16(yhi, bh, acc1[t], 0, 0, 0);
                    acc0[t] = __builtin_amdgcn_mfma_f32_16x16x32_bf16(xhi, bo, acc0[t], 0, 0, 0);
                    acc1[t] = __builtin_amdgcn_mfma_f32_16x16x32_bf16(yhi, bo, acc1[t], 0, 0, 0);
                    acc0[t] = __builtin_amdgcn_mfma_f32_16x16x32_bf16(xlo, bh, acc0[t], 0, 0, 0);
                    acc1[t] = __builtin_amdgcn_mfma_f32_16x16x32_bf16(ylo, bh, acc1[t], 0, 0, 0);
                }
                if (c + 1 < NCH) {
                    #pragma unroll
                    for (int i = 0; i < NX; ++i) xc[i] = xn[i];
                }
            }
        } else {
            // ---- LDS levels: A-frags read straight from hi/lo pairsum planes
            #pragma unroll 1
            for (int c = 0; c < NCH; ++c) {
                __syncthreads();
                if (c + 1 < NCH) stage(c + 1, (c + 1) & 1);
                if (actA) {
                    int kk = c * 32 + q * 8;
                    short8 xhi = {0,0,0,0,0,0,0,0}, xlo = xhi, yhi = xhi, ylo = xhi;
                    if (kk + 8 <= SROW_ST) {
                        xhi = *(const short8*)&sbuf[rowA * SROW_ST + kk];
                        xlo = *(const short8*)&sbuf[SPLANE_SH + rowA * SROW_ST + kk];
                        if (actB) {
                            yhi = *(const short8*)&sbuf[(rowA + 16) * SROW_ST + kk];
                            ylo = *(const short8*)&sbuf[SPLANE_SH + (rowA + 16) * SROW_ST + kk];
                        }
                    }
                    const short* bhp = &wbuf[(c & 1) * WB_SH + r * 32 + q * 8];
                    const short* bop = bhp + PLANE_SH;
                    if (actB) {
                        #pragma unroll
                        for (int t = 0; t < NT; ++t) {
                            short8 bh = *(const short8*)(bhp + t * 512);
                            short8 bo = *(const short8*)(bop + t * 512);
                            acc0[t] = __builtin_amdgcn_mfma_f32_16x16x32_bf16(xhi, bh, acc0[t], 0, 0, 0);
                            acc1[t] = __builtin_amdgcn_mfma_f32_16x16x32_bf16(yhi, bh, acc1[t], 0, 0, 0);
                            acc0[t] = __builtin_amdgcn_mfma_f32_16x16x32_bf16(xhi, bo, acc0[t], 0, 0, 0);
                            acc1[t] = __builtin_amdgcn_mfma_f32_16x16x32_bf16(yhi, bo, acc1[t], 0, 0, 0);
                            acc0[t] = __builtin_amdgcn_mfma_f32_16x16x32_bf16(xlo, bh, acc0[t], 0, 0, 0);
                            acc1[t] = __builtin_amdgcn_mfma_f32_16x16x32_bf16(ylo, bh, acc1[t], 0, 0, 0);
                        }
                    } else {
                        #pragma unroll
                        for (int t = 0; t < NT; ++t) {
                            short8 bh = *(const short8*)(bhp + t * 512);
                            short8 bo = *(const short8*)(bop + t * 512);
                            acc0[t] = __builtin_amdgcn_mfma_f32_16x16x32_bf16(xhi, bh, acc0[t], 0, 0, 0);
                            acc0[t] = __builtin_amdgcn_mfma_f32_16x16x32_bf16(xhi, bo, acc0[t], 0, 0, 0);
                            acc0[t] = __builtin_amdgcn_mfma_f32_16x16x32_bf16(xlo, bh, acc0[t], 0, 0, 0);
                        }
                    }
                }
            }
        }

        // ---- epilogue: bias + ReLU, pairsum -> sbuf (or s-seam global), pj partials
        __syncthreads();                          // all waves done reading wbuf & sbuf
        float* pjb = (float*)wbuf;                // 6144 f32 scratch in buffer 0
        if (actA) {
            float pj[2][4][3] = {};
            #pragma unroll
            for (int t = 0; t < NT; ++t) {
                int n = t * 16 + r;
                bool nok = n < DD;
                float w0 = nok ? Wp[n] : 0.f;
                float w1 = nok ? Wp[DD + n] : 0.f;
                float w2 = nok ? Wp[2 * DD + n] : 0.f;
                float b2 = nok ? 2.f * bl[n] : 0.f;
                float v0[4], v1[4];
                #pragma unroll
                for (int g = 0; g < 4; ++g) {
                    float a = acc0[t][g] + b2; v0[g] = a > 0.f ? a : 0.f;
                    float b = acc1[t][g] + b2; v1[g] = b > 0.f ? b : 0.f;
                    pj[0][g][0] += v0[g] * w0; pj[0][g][1] += v0[g] * w1; pj[0][g][2] += v0[g] * w2;
                    pj[1][g][0] += v1[g] * w0; pj[1][g][1] += v1[g] * w1; pj[1][g][2] += v1[g] * w2;
                }
                if (s < 3) {
                    int sr = wid * 16 + q * 2;
                    float sa = v0[0] + v0[1], sb = v0[2] + v0[3];
                    unsigned short h;
                    h = bf16_rne(sa);
                    sbuf[sr * SROW_ST + n] = (short)h;
                    sbuf[SPLANE_SH + sr * SROW_ST + n] = (short)bf16_rne(sa - bf16_to_f32(h));
                    h = bf16_rne(sb);
                    sbuf[(sr + 1) * SROW_ST + n] = (short)h;
                    sbuf[SPLANE_SH + (sr + 1) * SROW_ST + n] = (short)bf16_rne(sb - bf16_to_f32(h));
                    if (actB) {
                        sa = v1[0] + v1[1]; sb = v1[2] + v1[3];
                        h = bf16_rne(sa);
                        sbuf[(sr + 8) * SROW_ST + n] = (short)h;
                        sbuf[SPLANE_SH + (sr + 8) * SROW_ST + n] = (short)bf16_rne(sa - bf16_to_f32(h));
                        h = bf16_rne(sb);
                        sbuf[(sr + 9) * SROW_ST + n] = (short)h;
                        sbuf[SPLANE_SH + (sr + 9) * SROW_ST + n] = (short)bf16_rne(sb - bf16_to_f32(h));
                    }
                } else if (sdst) {
                    if (nok) {
                        int sr = blk * 8 + q * 2;
                        sdst[(size_t)sr * DD + n]       = v0[0] + v0[1];
                        sdst[(size_t)(sr + 1) * DD + n] = v0[2] + v0[3];
                    }
                }
            }
            #pragma unroll
            for (int h2 = 0; h2 < 2; ++h2)
                #pragma unroll
                for (int g = 0; g < 4; ++g)
                    #pragma unroll
                    for (int cc = 0; cc < 3; ++cc)
                        pjb[(((((wid * 2 + h2) * 4 + q) * 4 + g) * 16) + r) * 3 + cc] = pj[h2][g][cc];
        }
        __syncthreads();
        if (tid < n_l) {
            int w2 = tid >> 5, h2 = (tid >> 4) & 1, q2 = (tid >> 2) & 3, g2 = tid & 3;
            const float* base = &pjb[((((w2 * 2 + h2) * 4 + q2) * 4 + g2) * 16) * 3];
            float s0 = 0.f, s1 = 0.f, s2 = 0.f;
            #pragma unroll
            for (int rr = 0; rr < 16; ++rr) {
                s0 += base[rr * 3]; s1 += base[rr * 3 + 1]; s2 += base[rr * 3 + 2];
            }
            int la = l_entry + s;
            int lg = 12 - la;
            int offk = 8192 - (8192 >> la);
            int g_row = blk * n_l + tid;
            int b = g_row >> lg, n2 = g_row & ((1 << lg) - 1);
            float* o = out + ((size_t)b * 8191 + offk + n2) * 3;
            o[0] = s0 + bp[0]; o[1] = s1 + bp[1]; o[2] = s2 + bp[2];
        }

        if (MODE == 0 && s == 0) {
            // level-0 projection: reduce pr over the 4 q-groups, write 256 leaves/block
            #pragma unroll
            for (int j = 0; j < 4; ++j)
                #pragma unroll
                for (int cc = 0; cc < 3; ++cc) {
                    float v = pr[j][cc];
                    v += __shfl_xor(v, 16);
                    v += __shfl_xor(v, 32);
                    pr[j][cc] = v;
                }
            if (q == 0) {
                long mA = (long)blk * 128 + wid * 32 + r;
                #pragma unroll
                for (int j = 0; j < 4; ++j) {
                    long gr = 2 * mA + (j >> 1) * 32 + (j & 1);
                    int b = (int)(gr >> 12), n = (int)(gr & 4095);
                    float* o = out + ((size_t)b * 8191 + n) * 3;
                    o[0] = pr[j][0] + bp[0];
                    o[1] = pr[j][1] + bp[1];
                    o[2] = pr[j][2] + bp[2];
                }
            }
        }
    }
}

extern "C" void kernel_launch(void* const* d_in, const int* in_sizes, int n_in,
                              void* d_out, int out_size, void* d_ws, size_t ws_size,
                              hipStream_t stream)
{
    const int*   word_ids  = (const int*)d_in[0];    // (32, 4096) int32
    const float* embedding = (const float*)d_in[1];  // (50000, 300) f32
    const float* Wl        = (const float*)d_in[2];  // (300, 300) f32
    const float* bl        = (const float*)d_in[3];  // (300,) f32
    const float* Wp        = (const float*)d_in[4];  // (3, 300) f32
    const float* bp        = (const float*)d_in[5];  // (3,) f32
    float* out = (float*)d_out;

    // ws: Whi (204800 B) | Wlo (204800 B) | s4 (4096x300 f32) | s8 (256x300 f32)
    char* ws = (char*)d_ws;
    short* Whi = (short*)ws;
    short* Wlo = Whi + KP * KP;
    float* s4  = (float*)(ws + 2 * KP * KP * 2);
    float* s8  = (float*)(ws + 2 * KP * KP * 2 + 4096 * DD * 4);

    split_w<<<(KP * KP + 255) / 256, 256, 0, stream>>>(Wl, Whi, Wlo);

    // A: level-0 proj + levels 1..4 (65536 L1 rows, 128/block)
    tree_fused<0><<<512, 256, 0, stream>>>(embedding, word_ids, Whi, Wlo, bl, Wp, bp, out, s4, 1);
    // B: levels 5..8 (4096 rows, 128/block)
    tree_fused<1><<<32, 256, 0, stream>>>(s4, nullptr, Whi, Wlo, bl, Wp, bp, out, s8, 5);
    // C: levels 9..12 (256 rows, 128/block)
    tree_fused<1><<<2, 256, 0, stream>>>(s8, nullptr, Whi, Wlo, bl, Wp, bp, out, nullptr, 9);
}

// Round 2
// 419.312 us; speedup vs baseline: 1.6671x; 1.6120x over previous
//
#include <hip/hip_runtime.h>

#define DD 300
#define KP 320                      // padded K (10 chunks of 32)
#define NT 19                       // n-tiles of 16 (covers 304)
#define NCH 10                      // k-chunks
#define PLANE_SH 9728               // shorts per W plane-chunk: 304 rows x 32 k
#define WB_SH (2 * PLANE_SH)        // one staging buffer (hi+lo) = 19456 shorts
#define SROW_ST 312                 // shorts per s-row: 16B-aligned stride
#define SPLANE_SH (64 * SROW_ST)    // 19968 shorts per s plane (64 rows)

typedef __attribute__((ext_vector_type(8))) short short8;
typedef __attribute__((ext_vector_type(4))) float f32x4;

__device__ __forceinline__ unsigned short bf16_rne(float x) {
    union { float f; unsigned u; } v; v.f = x;
    v.u += 0x7FFF + ((v.u >> 16) & 1);
    return (unsigned short)(v.u >> 16);
}
__device__ __forceinline__ float bf16_to_f32(unsigned short h) {
    union { unsigned u; float f; } v; v.u = (unsigned)h << 16;
    return v.f;
}

// async global->LDS, 16B per lane; LDS dest = uniform base + lane*16
__device__ __forceinline__ void gload_lds16(const void* g, void* l) {
    __builtin_amdgcn_global_load_lds(
        (const __attribute__((address_space(1))) unsigned*)g,
        (__attribute__((address_space(3))) unsigned*)l, 16, 0, 0);
}

// split Wl (n,k == B-frag layout) into padded bf16 hi/lo planes [KP][KP]
__global__ void split_w(const float* __restrict__ Wl, short* __restrict__ Whi, short* __restrict__ Wlo) {
    int idx = blockIdx.x * 256 + threadIdx.x;
    if (idx >= KP * KP) return;
    int n = idx / KP, k = idx % KP;
    float v = (n < DD && k < DD) ? Wl[n * DD + k] : 0.f;
    unsigned short hi = bf16_rne(v);
    Whi[idx] = (short)hi;
    Wlo[idx] = (short)bf16_rne(v - bf16_to_f32(hi));
}

// Fused sub-tree kernel, 8 waves x 16 rows = 128 entry rows per block.
// SLEV levels per block (rows halve each level; below 16 rows one partial
// 16-row MFMA tile is used, garbage rows provably discarded: W pad keeps
// pad cols exactly 0, stale sbuf rows are finite and never read as valid).
// W chunk double-buffered via global_load_lds -> one barrier per chunk.
// MODE 0: gather-pair entry (embedding+ids) + fused level-0 projection.
template<int MODE, int SLEV>
__global__ __launch_bounds__(512, 1) void tree_fused(
    const float* __restrict__ src, const int* __restrict__ ids,
    const short* __restrict__ Whi, const short* __restrict__ Wlo,
    const float* __restrict__ bl, const float* __restrict__ Wp,
    const float* __restrict__ bp, float* __restrict__ out,
    float* __restrict__ sdst, int l_entry)
{
    __shared__ __align__(16) short wbuf[2 * WB_SH];       // 77824 B (buf0 reused as pj scratch)
    __shared__ __align__(16) short sbuf[2 * SPLANE_SH];   // 79872 B: hi | lo pairsum planes
    const int tid = threadIdx.x;
    const int wid = tid >> 6, lane = tid & 63;
    const int r = lane & 15, q = lane >> 4;
    const int blk = blockIdx.x;

    // zero the k-pad cols [304,312) of both s planes (read by chunk 9, q==2)
    for (int i = tid; i < 64 * 8 * 2; i += 512) {
        int pl = i >> 9, j = i & 511;
        sbuf[pl * SPLANE_SH + (j >> 3) * SROW_ST + 304 + (j & 7)] = 0;
    }

    auto stage = [&](int c, int bsel) {
        short* wb = &wbuf[bsel * WB_SH];
        #pragma unroll
        for (int t2i = 0; t2i < 5; ++t2i) {
            int t2 = wid + t2i * 8;                // wave-uniform piece id
            if (t2 < 2 * NT) {
                int pl = t2 >= NT ? 1 : 0;
                int ss = t2 - pl * NT;
                const short* gp = (pl ? Wlo : Whi)
                    + (long)(ss * 16 + (lane >> 2)) * KP + c * 32 + (lane & 3) * 8;
                gload_lds16(gp, &wb[pl * PLANE_SH + ss * 512]);
            }
        }
    };

    float pr[2][3] = {};          // MODE0: level-0 projection partials (2 leaves/lane)
    f32x4 acc[NT];

    #pragma unroll 1
    for (int s = 0; s < SLEV; ++s) {
        const int n_l = 128 >> s;                 // valid rows at this level
        const bool actA = (wid * 16) < n_l;
        const int rowA = wid * 16 + r;

        #pragma unroll
        for (int t = 0; t < NT; ++t)
            #pragma unroll
            for (int i = 0; i < 4; ++i) acc[t][i] = 0.f;

        __syncthreads();                          // wbuf free (reducers done), sbuf visible
        stage(0, 0);

        if (s == 0) {
            // ---- entry level: x from global (gathered leaf pairs or direct rows)
            const float *p0, *p1;
            {
                long mA = (long)blk * 128 + rowA;
                if (MODE == 0) {
                    p0 = src + (long)ids[2 * mA] * DD;
                    p1 = src + (long)ids[2 * mA + 1] * DD;
                } else {
                    p0 = src + mA * DD; p1 = p0;
                }
            }
            f32x4 xc[4], xn[4];
            auto loadx = [&](int c, f32x4* x) {
                int kk = c * 32 + q * 8;
                if (kk + 8 <= DD) {
                    x[0] = *(const f32x4*)(p0 + kk); x[1] = *(const f32x4*)(p0 + kk + 4);
                    if (MODE == 0) { x[2] = *(const f32x4*)(p1 + kk); x[3] = *(const f32x4*)(p1 + kk + 4); }
                } else {
                    #pragma unroll
                    for (int i = 0; i < 8; ++i) {
                        int kg = kk + i;
                        x[i >> 2][i & 3] = (kg < DD) ? p0[kg] : 0.f;
                        if (MODE == 0) x[2 + (i >> 2)][i & 3] = (kg < DD) ? p1[kg] : 0.f;
                    }
                }
            };
            loadx(0, xc);
            #pragma unroll 1
            for (int c = 0; c < NCH; ++c) {
                __syncthreads();                  // buf[c&1] staged (vmcnt drained) & visible
                if (c + 1 < NCH) { stage(c + 1, (c + 1) & 1); loadx(c + 1, xn); }
                f32x4 s0v, s1v;
                if (MODE == 0) { s0v = xc[0] + xc[2]; s1v = xc[1] + xc[3]; }
                else           { s0v = xc[0];         s1v = xc[1]; }
                short8 xhi, xlo;
                #pragma unroll
                for (int i = 0; i < 4; ++i) {
                    unsigned short h; float v;
                    v = s0v[i]; h = bf16_rne(v); xhi[i]     = (short)h; xlo[i]     = (short)bf16_rne(v - bf16_to_f32(h));
                    v = s1v[i]; h = bf16_rne(v); xhi[4 + i] = (short)h; xlo[4 + i] = (short)bf16_rne(v - bf16_to_f32(h));
                }
                if (MODE == 0) {
                    int kk = c * 32 + q * 8;
                    #pragma unroll
                    for (int i = 0; i < 8; ++i) {
                        int kg = kk + i;
                        float w0 = (kg < DD) ? Wp[kg] : 0.f;
                        float w1 = (kg < DD) ? Wp[DD + kg] : 0.f;
                        float w2 = (kg < DD) ? Wp[2 * DD + kg] : 0.f;
                        float xa = xc[i >> 2][i & 3];
                        float xb = xc[2 + (i >> 2)][i & 3];
                        pr[0][0] += xa * w0; pr[0][1] += xa * w1; pr[0][2] += xa * w2;
                        pr[1][0] += xb * w0; pr[1][1] += xb * w1; pr[1][2] += xb * w2;
                    }
                }
                const short* bhp = &wbuf[(c & 1) * WB_SH + r * 32 + q * 8];
                const short* bop = bhp + PLANE_SH;
                #pragma unroll
                for (int t = 0; t < NT; ++t) {
                    short8 bh = *(const short8*)(bhp + t * 512);
                    short8 bo = *(const short8*)(bop + t * 512);
                    acc[t] = __builtin_amdgcn_mfma_f32_16x16x32_bf16(xhi, bh, acc[t], 0, 0, 0);
                    acc[t] = __builtin_amdgcn_mfma_f32_16x16x32_bf16(xhi, bo, acc[t], 0, 0, 0);
                    acc[t] = __builtin_amdgcn_mfma_f32_16x16x32_bf16(xlo, bh, acc[t], 0, 0, 0);
                }
                if (c + 1 < NCH) {
                    #pragma unroll
                    for (int i = 0; i < 4; ++i) xc[i] = xn[i];
                }
            }
        } else {
            // ---- LDS levels: A-frags straight from hi/lo pairsum planes
            #pragma unroll 1
            for (int c = 0; c < NCH; ++c) {
                __syncthreads();
                if (c + 1 < NCH) stage(c + 1, (c + 1) & 1);
                if (actA) {
                    int kk = c * 32 + q * 8;
                    short8 xhi = {0,0,0,0,0,0,0,0}, xlo = xhi;
                    if (kk + 8 <= SROW_ST) {
                        xhi = *(const short8*)&sbuf[rowA * SROW_ST + kk];
                        xlo = *(const short8*)&sbuf[SPLANE_SH + rowA * SROW_ST + kk];
                    }
                    const short* bhp = &wbuf[(c & 1) * WB_SH + r * 32 + q * 8];
                    const short* bop = bhp + PLANE_SH;
                    #pragma unroll
                    for (int t = 0; t < NT; ++t) {
                        short8 bh = *(const short8*)(bhp + t * 512);
                        short8 bo = *(const short8*)(bop + t * 512);
                        acc[t] = __builtin_amdgcn_mfma_f32_16x16x32_bf16(xhi, bh, acc[t], 0, 0, 0);
                        acc[t] = __builtin_amdgcn_mfma_f32_16x16x32_bf16(xhi, bo, acc[t], 0, 0, 0);
                        acc[t] = __builtin_amdgcn_mfma_f32_16x16x32_bf16(xlo, bh, acc[t], 0, 0, 0);
                    }
                }
            }
        }

        // ---- epilogue: bias + ReLU, pairsum -> sbuf (or seam global), pj partials
        __syncthreads();                          // all waves done reading wbuf & sbuf
        float* pjb = (float*)wbuf;                // [row128][r16][3] f32 scratch (24 KB)
        if (actA) {
            float pj[4][3] = {};
            #pragma unroll
            for (int t = 0; t < NT; ++t) {
                int n = t * 16 + r;
                bool nok = n < DD;
                float w0 = nok ? Wp[n] : 0.f;
                float w1 = nok ? Wp[DD + n] : 0.f;
                float w2 = nok ? Wp[2 * DD + n] : 0.f;
                float b2 = nok ? 2.f * bl[n] : 0.f;
                float v[4];
                #pragma unroll
                for (int g = 0; g < 4; ++g) {
                    float a = acc[t][g] + b2; v[g] = a > 0.f ? a : 0.f;
                    pj[g][0] += v[g] * w0; pj[g][1] += v[g] * w1; pj[g][2] += v[g] * w2;
                }
                if (s + 1 < SLEV) {
                    // n in [300,304) gets exact 0 (W pad) -> safe unguarded write
                    int sr = wid * 8 + q * 2;
                    float sa = v[0] + v[1], sb = v[2] + v[3];
                    unsigned short h;
                    h = bf16_rne(sa);
                    sbuf[sr * SROW_ST + n] = (short)h;
                    sbuf[SPLANE_SH + sr * SROW_ST + n] = (short)bf16_rne(sa - bf16_to_f32(h));
                    h = bf16_rne(sb);
                    sbuf[(sr + 1) * SROW_ST + n] = (short)h;
                    sbuf[SPLANE_SH + (sr + 1) * SROW_ST + n] = (short)bf16_rne(sb - bf16_to_f32(h));
                } else if (sdst != nullptr) {
                    if (nok) {
                        int sr = blk * 8 + q * 2;
                        sdst[(size_t)sr * DD + n]       = v[0] + v[1];
                        sdst[(size_t)(sr + 1) * DD + n] = v[2] + v[3];
                    }
                }
            }
            #pragma unroll
            for (int g = 0; g < 4; ++g)
                #pragma unroll
                for (int cc = 0; cc < 3; ++cc)
                    pjb[((wid * 16 + q * 4 + g) * 16 + r) * 3 + cc] = pj[g][cc];
        }
        __syncthreads();
        if (tid < n_l) {
            const float* base = &pjb[tid * 48];
            float o0 = 0.f, o1 = 0.f, o2 = 0.f;
            #pragma unroll
            for (int rr = 0; rr < 16; ++rr) {
                o0 += base[rr * 3]; o1 += base[rr * 3 + 1]; o2 += base[rr * 3 + 2];
            }
            int la = l_entry + s;
            int lg = 12 - la;
            int offk = 8192 - (8192 >> la);
            int g_row = blk * n_l + tid;
            int b = g_row >> lg, n2 = g_row & ((1 << lg) - 1);
            float* o = out + ((size_t)b * 8191 + offk + n2) * 3;
            o[0] = o0 + bp[0]; o[1] = o1 + bp[1]; o[2] = o2 + bp[2];
        }

        if (MODE == 0 && s == 0) {
            // level-0 projection: reduce pr over the 4 q-groups, 256 leaves/block
            #pragma unroll
            for (int j = 0; j < 2; ++j)
                #pragma unroll
                for (int cc = 0; cc < 3; ++cc) {
                    float v = pr[j][cc];
                    v += __shfl_xor(v, 16);
                    v += __shfl_xor(v, 32);
                    pr[j][cc] = v;
                }
            if (q == 0) {
                long mA = (long)blk * 128 + wid * 16 + r;
                #pragma unroll
                for (int j = 0; j < 2; ++j) {
                    long gr = 2 * mA + j;
                    int b = (int)(gr >> 12), n = (int)(gr & 4095);
                    float* o = out + ((size_t)b * 8191 + n) * 3;
                    o[0] = pr[j][0] + bp[0];
                    o[1] = pr[j][1] + bp[1];
                    o[2] = pr[j][2] + bp[2];
                }
            }
        }
    }
}

extern "C" void kernel_launch(void* const* d_in, const int* in_sizes, int n_in,
                              void* d_out, int out_size, void* d_ws, size_t ws_size,
                              hipStream_t stream)
{
    const int*   word_ids  = (const int*)d_in[0];    // (32, 4096) int32
    const float* embedding = (const float*)d_in[1];  // (50000, 300) f32
    const float* Wl        = (const float*)d_in[2];  // (300, 300) f32
    const float* bl        = (const float*)d_in[3];  // (300,) f32
    const float* Wp        = (const float*)d_in[4];  // (3, 300) f32
    const float* bp        = (const float*)d_in[5];  // (3,) f32
    float* out = (float*)d_out;

    // ws: Whi (204800 B) | Wlo (204800 B) | s4 (4096x300 f32)
    char* ws = (char*)d_ws;
    short* Whi = (short*)ws;
    short* Wlo = Whi + KP * KP;
    float* s4  = (float*)(ws + 2 * KP * KP * 2);

    split_w<<<(KP * KP + 255) / 256, 256, 0, stream>>>(Wl, Whi, Wlo);

    // A: level-0 proj + levels 1..4 (65536 L1 rows, 128/block, 8 waves)
    tree_fused<0, 4><<<512, 512, 0, stream>>>(embedding, word_ids, Whi, Wlo, bl, Wp, bp, out, s4, 1);
    // B: levels 5..12 (each block owns one batch's full subtree: 128 -> 1 rows)
    tree_fused<1, 8><<<32, 512, 0, stream>>>(s4, nullptr, Whi, Wlo, bl, Wp, bp, out, nullptr, 5);
}